// Round 4
// baseline (1450.075 us; speedup 1.0000x reference)
//
#include <hip/hip_runtime.h>
#include <hip/hip_bf16.h>
#include <math.h>

#define NN     100000
#define NFEATD 512
#define NHIDD  256
#define NCLS   40
#define NE     1600000
#define KHOP   10

typedef __attribute__((ext_vector_type(8))) short short8;
typedef __attribute__((ext_vector_type(4))) float floatx4;

// ---------- helpers ----------
static __device__ __forceinline__ float bf2f(unsigned int u) {
  unsigned int x = u << 16;
  float f;
  __builtin_memcpy(&f, &x, 4);
  return f;
}
static __device__ __forceinline__ unsigned short f2bf(float f) {
  unsigned int x;
  __builtin_memcpy(&x, &f, 4);
  x = (x + 0x7fffu + ((x >> 16) & 1u)) >> 16;
  return (unsigned short)x;
}
// 4 uints (8 packed bf16) -> 8 floats
static __device__ __forceinline__ void bf8_to_f(const uint4 u, float* f) {
  unsigned int a0 = u.x, a1 = u.y, a2 = u.z, a3 = u.w;
  unsigned int t;
  t = a0 << 16;          __builtin_memcpy(&f[0], &t, 4);
  t = a0 & 0xffff0000u;  __builtin_memcpy(&f[1], &t, 4);
  t = a1 << 16;          __builtin_memcpy(&f[2], &t, 4);
  t = a1 & 0xffff0000u;  __builtin_memcpy(&f[3], &t, 4);
  t = a2 << 16;          __builtin_memcpy(&f[4], &t, 4);
  t = a2 & 0xffff0000u;  __builtin_memcpy(&f[5], &t, 4);
  t = a3 << 16;          __builtin_memcpy(&f[6], &t, 4);
  t = a3 & 0xffff0000u;  __builtin_memcpy(&f[7], &t, 4);
}

// ---------- W1 [512][256] fp32 -> Wt [256][512] bf16 ----------
__global__ __launch_bounds__(256) void wt_kernel(const float* __restrict__ W1,
                                                 unsigned short* __restrict__ Wt) {
  int i = blockIdx.x * 256 + threadIdx.x;  // over 512*256
  int k = i >> 8;
  int n = i & 255;
  Wt[n * 512 + k] = f2bf(W1[i]);
}

// ---------- GEMM1 (MFMA, software-pipelined): h1 = relu(x @ W1 + b1) ----------
// 128x128 tile, 256 threads = 4 waves (2x2), each wave 64x64 via 4x4 mfma 16x16x32.
__global__ __launch_bounds__(256) void gemm1_mfma_kernel(
    const float* __restrict__ x, const unsigned short* __restrict__ Wt,
    const float* __restrict__ b1, unsigned short* __restrict__ h1) {
  __shared__ unsigned short As[128 * 40];  // row stride 40 shorts (80B)
  __shared__ unsigned short Bs[128 * 40];
  const int tid = threadIdx.x;
  const int lane = tid & 63;
  const int wave = tid >> 6;
  const int wr = wave >> 1, wc = wave & 1;
  const int m = lane & 15, quad = lane >> 4;
  const int c0 = blockIdx.x * 128;  // col block (0 or 128)
  const int r0 = blockIdx.y * 128;  // row block

  const int arow = tid >> 3;   // 0..31 (+rep*32)
  const int akq = tid & 7;     // float4 index within row (k = akq*4)
  const int brow = tid >> 2;   // 0..63 (+rep*64)
  const int bkq = tid & 3;     // 16B chunk within row (k = bkq*8)

  floatx4 acc[4][4];
#pragma unroll
  for (int i = 0; i < 4; ++i)
#pragma unroll
    for (int j = 0; j < 4; ++j) acc[i][j] = (floatx4){0.f, 0.f, 0.f, 0.f};

  float4 aR[4];
  uint4 bR[2];
#pragma unroll
  for (int rep = 0; rep < 4; ++rep) {
    int grow = r0 + arow + rep * 32;
    aR[rep] = make_float4(0.f, 0.f, 0.f, 0.f);
    if (grow < NN) aR[rep] = *(const float4*)(x + grow * NFEATD + akq * 4);
  }
#pragma unroll
  for (int rep = 0; rep < 2; ++rep)
    bR[rep] = *(const uint4*)(Wt + (c0 + brow + rep * 64) * NFEATD + bkq * 8);

  for (int kt = 0; kt < NFEATD; kt += 32) {
#pragma unroll
    for (int rep = 0; rep < 4; ++rep) {
      ushort4 o;
      o.x = f2bf(aR[rep].x);
      o.y = f2bf(aR[rep].y);
      o.z = f2bf(aR[rep].z);
      o.w = f2bf(aR[rep].w);
      *(ushort4*)&As[(arow + rep * 32) * 40 + akq * 4] = o;
    }
#pragma unroll
    for (int rep = 0; rep < 2; ++rep)
      *(uint4*)&Bs[(brow + rep * 64) * 40 + bkq * 8] = bR[rep];
    __syncthreads();

    int ktn = kt + 32;
    if (ktn < NFEATD) {
#pragma unroll
      for (int rep = 0; rep < 4; ++rep) {
        int grow = r0 + arow + rep * 32;
        float4 v = make_float4(0.f, 0.f, 0.f, 0.f);
        if (grow < NN) v = *(const float4*)(x + grow * NFEATD + ktn + akq * 4);
        aR[rep] = v;
      }
#pragma unroll
      for (int rep = 0; rep < 2; ++rep)
        bR[rep] = *(const uint4*)(Wt + (c0 + brow + rep * 64) * NFEATD + ktn + bkq * 8);
    }

    short8 af[4], bfr[4];
#pragma unroll
    for (int i = 0; i < 4; ++i)
      af[i] = *(const short8*)&As[(wr * 64 + i * 16 + m) * 40 + quad * 8];
#pragma unroll
    for (int j = 0; j < 4; ++j)
      bfr[j] = *(const short8*)&Bs[(wc * 64 + j * 16 + m) * 40 + quad * 8];
#pragma unroll
    for (int i = 0; i < 4; ++i)
#pragma unroll
      for (int j = 0; j < 4; ++j)
        acc[i][j] = __builtin_amdgcn_mfma_f32_16x16x32_bf16(af[i], bfr[j], acc[i][j], 0, 0, 0);
    __syncthreads();
  }

  float bias[4];
#pragma unroll
  for (int j = 0; j < 4; ++j) bias[j] = b1[c0 + wc * 64 + j * 16 + m];
#pragma unroll
  for (int i = 0; i < 4; ++i) {
#pragma unroll
    for (int r = 0; r < 4; ++r) {
      int row = r0 + wr * 64 + i * 16 + quad * 4 + r;
      if (row < NN) {
#pragma unroll
        for (int j = 0; j < 4; ++j) {
          float v = acc[i][j][r] + bias[j];
          h1[row * NHIDD + c0 + wc * 64 + j * 16 + m] = f2bf(fmaxf(v, 0.f));
        }
      }
    }
  }
}

// ---------- GEMM2: hb(bf16) = h1(bf16) @ W2 + b2 ----------
__global__ __launch_bounds__(256) void gemm2_kernel(
    const unsigned short* __restrict__ h1, const float* __restrict__ W2,
    const float* __restrict__ b2, unsigned short* __restrict__ hb) {
  __shared__ float w2s[NHIDD * NCLS];  // 40 KB
  __shared__ float b2s[NCLS];
  __shared__ unsigned short h1s[64 * 264];  // padded stride
  const int tid = threadIdx.x;
  const int r0 = blockIdx.x * 64;
  for (int i = tid; i < NHIDD * NCLS; i += 256) w2s[i] = W2[i];
  if (tid < NCLS) b2s[tid] = b2[tid];
#pragma unroll
  for (int q = 0; q < 8; ++q) {
    int l = tid + q * 256;
    int lr = l >> 5;
    int lc = (l & 31) << 3;
    int row = r0 + lr;
    uint4 v = make_uint4(0, 0, 0, 0);
    if (row < NN) v = *(const uint4*)(h1 + row * NHIDD + lc);
    *(uint4*)&h1s[lr * 264 + lc] = v;
  }
  __syncthreads();
  const int lr = tid >> 2;
  const int cq = (tid & 3) * 10;
  float acc[10];
#pragma unroll
  for (int j = 0; j < 10; ++j) acc[j] = 0.f;
#pragma unroll 4
  for (int k = 0; k < NHIDD; k += 2) {
    unsigned int hp = *(const unsigned int*)&h1s[lr * 264 + k];
    float a0 = bf2f(hp & 0xffffu);
    float a1 = bf2f(hp >> 16);
    const float* w0 = &w2s[k * NCLS + cq];
    const float* w1 = &w2s[(k + 1) * NCLS + cq];
#pragma unroll
    for (int j = 0; j < 10; ++j)
      acc[j] = fmaf(a1, w1[j], fmaf(a0, w0[j], acc[j]));
  }
  int row = r0 + lr;
  if (row < NN) {
#pragma unroll
    for (int jj = 0; jj < 5; ++jj) {
      unsigned int u = (unsigned int)f2bf(acc[2 * jj] + b2s[cq + 2 * jj]) |
                       ((unsigned int)f2bf(acc[2 * jj + 1] + b2s[cq + 2 * jj + 1]) << 16);
      *(unsigned int*)&hb[row * NCLS + cq + 2 * jj] = u;
    }
  }
}

// ---------- CSR build (degree-sorted row order) ----------
__global__ __launch_bounds__(256) void zero_kernel(int* __restrict__ p, int n) {
  int i = blockIdx.x * 256 + threadIdx.x;
  if (i < n) p[i] = 0;
}
__global__ __launch_bounds__(256) void count_kernel(const int* __restrict__ edst,
                                                    int* __restrict__ counts) {
  int e = blockIdx.x * 256 + threadIdx.x;
  if (e < NE) atomicAdd(&counts[edst[e]], 1);
}
__global__ __launch_bounds__(256) void hist_kernel(const int* __restrict__ counts,
                                                   int* __restrict__ binoff) {
  int r = blockIdx.x * 256 + threadIdx.x;
  if (r < NN) {
    int d = counts[r];
    if (d > 63) d = 63;
    atomicAdd(&binoff[d], 1);
  }
}
__global__ __launch_bounds__(64) void binscan_kernel(int* __restrict__ binoff) {
  __shared__ int s[64];
  int t = threadIdx.x;
  s[t] = binoff[t];
  __syncthreads();
  if (t == 0) {
    int run = 0;
    for (int i = 0; i < 64; ++i) {
      int c = s[i];
      s[i] = run;
      run += c;
    }
  }
  __syncthreads();
  binoff[t] = s[t];
}
__global__ __launch_bounds__(256) void scatter_rows_kernel(
    const int* __restrict__ counts, int* __restrict__ binoff,
    int* __restrict__ perm, int* __restrict__ spos) {
  int r = blockIdx.x * 256 + threadIdx.x;
  if (r < NN) {
    int d = counts[r];
    if (d > 63) d = 63;
    int pos = atomicAdd(&binoff[d], 1);
    perm[pos] = r;
    spos[r] = pos;
  }
}
__global__ __launch_bounds__(256) void scan_blocks_kernel(
    const int* __restrict__ counts, const int* __restrict__ perm,
    int* __restrict__ srs, int* __restrict__ bsum) {
  __shared__ int s[256];
  int gid = blockIdx.x * 256 + threadIdx.x;
  int v = (gid < NN) ? counts[perm[gid]] : 0;
  s[threadIdx.x] = v;
  __syncthreads();
  for (int off = 1; off < 256; off <<= 1) {
    int t = (threadIdx.x >= off) ? s[threadIdx.x - off] : 0;
    __syncthreads();
    s[threadIdx.x] += t;
    __syncthreads();
  }
  if (gid < NN) srs[gid + 1] = s[threadIdx.x];
  if (threadIdx.x == 255) bsum[blockIdx.x] = s[255];
}
#define NB 391
__global__ __launch_bounds__(512) void scan_sums_kernel(int* __restrict__ bsum) {
  __shared__ int s[512];
  int tid = threadIdx.x;
  int v = (tid < NB) ? bsum[tid] : 0;
  s[tid] = v;
  __syncthreads();
  for (int off = 1; off < 512; off <<= 1) {
    int t = (tid >= off) ? s[tid - off] : 0;
    __syncthreads();
    s[tid] += t;
    __syncthreads();
  }
  if (tid < NB) bsum[tid] = (tid == 0) ? 0 : s[tid - 1];  // exclusive
}
__global__ __launch_bounds__(256) void add_off_kernel(int* __restrict__ srs,
                                                      const int* __restrict__ bsum) {
  int gid = blockIdx.x * 256 + threadIdx.x;
  if (gid < NN) srs[gid + 1] += bsum[blockIdx.x];
  if (gid == 0) srs[0] = 0;
}
__global__ __launch_bounds__(256) void scatter_kernel(
    const int* __restrict__ esrc, const int* __restrict__ edst,
    const float* __restrict__ eval, const int* __restrict__ srs,
    const int* __restrict__ spos, int* __restrict__ cursor,
    int2* __restrict__ csr_pair) {
  int e = blockIdx.x * 256 + threadIdx.x;
  if (e < NE) {
    int p = spos[edst[e]];
    int idx = srs[p] + atomicAdd(&cursor[p], 1);
    csr_pair[idx] = make_int2(esrc[e], __float_as_int(eval[e]));
  }
}

// ---------- propagation: zo[r] = 0.9 * (A z)[r] + 0.1 * h[r], bf16 ----------
// thread t -> sorted-pos p = t/5, col-group cg = t%5 (8 cols, 16B bf16 gather)
__global__ __launch_bounds__(256) void prop_kernel(
    const int* __restrict__ srs, const int* __restrict__ perm,
    const int2* __restrict__ csr_pair, const unsigned short* __restrict__ zi,
    const unsigned short* __restrict__ hb, unsigned short* __restrict__ zo) {
  int t = blockIdx.x * 256 + threadIdx.x;
  if (t >= NN * 5) return;
  unsigned int p = (unsigned int)t / 5u;
  int cg8 = (t - (int)p * 5) * 8;  // col offset in bf16 elems
  int e0 = srs[p], e1 = srs[p + 1];
  int r = perm[p];
  float acc[8];
#pragma unroll
  for (int j = 0; j < 8; ++j) acc[j] = 0.f;

  int e = e0;
  for (; e + 8 <= e1; e += 8) {
    int2 pr[8];
#pragma unroll
    for (int q = 0; q < 8; ++q) pr[q] = csr_pair[e + q];
    uint4 g[8];
#pragma unroll
    for (int q = 0; q < 8; ++q)
      g[q] = *(const uint4*)(zi + pr[q].x * NCLS + cg8);
#pragma unroll
    for (int q = 0; q < 8; ++q) {
      float zf[8];
      bf8_to_f(g[q], zf);
      float v = __int_as_float(pr[q].y);
#pragma unroll
      for (int j = 0; j < 8; ++j) acc[j] = fmaf(v, zf[j], acc[j]);
    }
  }
  for (; e < e1; ++e) {
    int2 pr = csr_pair[e];
    uint4 g = *(const uint4*)(zi + pr.x * NCLS + cg8);
    float zf[8];
    bf8_to_f(g, zf);
    float v = __int_as_float(pr.y);
#pragma unroll
    for (int j = 0; j < 8; ++j) acc[j] = fmaf(v, zf[j], acc[j]);
  }

  uint4 hu = *(const uint4*)(hb + r * NCLS + cg8);
  float hf[8];
  bf8_to_f(hu, hf);
  uint4 o;
  unsigned int w[4];
#pragma unroll
  for (int i = 0; i < 4; ++i) {
    unsigned int lo = f2bf(0.9f * acc[2 * i] + 0.1f * hf[2 * i]);
    unsigned int hi = f2bf(0.9f * acc[2 * i + 1] + 0.1f * hf[2 * i + 1]);
    w[i] = lo | (hi << 16);
  }
  o.x = w[0];
  o.y = w[1];
  o.z = w[2];
  o.w = w[3];
  *(uint4*)(zo + r * NCLS + cg8) = o;
}

// ---------- log_softmax: bf16 z -> fp32 out ----------
__global__ __launch_bounds__(256) void lsm_kernel(const unsigned short* __restrict__ zf,
                                                  float* __restrict__ out) {
  int r = blockIdx.x * 256 + threadIdx.x;
  if (r >= NN) return;
  float v[NCLS];
#pragma unroll
  for (int q = 0; q < 5; ++q) {
    uint4 u = *(const uint4*)(zf + r * NCLS + q * 8);
    bf8_to_f(u, v + q * 8);
  }
  float m = v[0];
#pragma unroll
  for (int i = 1; i < NCLS; ++i) m = fmaxf(m, v[i]);
  float ssum = 0.f;
#pragma unroll
  for (int i = 0; i < NCLS; ++i) ssum += expf(v[i] - m);
  float lse = m + logf(ssum);
#pragma unroll
  for (int q = 0; q < 10; ++q) {
    float4 o;
    o.x = v[q * 4 + 0] - lse;
    o.y = v[q * 4 + 1] - lse;
    o.z = v[q * 4 + 2] - lse;
    o.w = v[q * 4 + 3] - lse;
    *(float4*)(out + r * NCLS + q * 4) = o;
  }
}

extern "C" void kernel_launch(void* const* d_in, const int* in_sizes, int n_in,
                              void* d_out, int out_size, void* d_ws, size_t ws_size,
                              hipStream_t stream) {
  const float* x = (const float*)d_in[0];
  const int* esrc = (const int*)d_in[1];
  const int* edst = (const int*)d_in[2];
  const float* eval = (const float*)d_in[3];
  const float* W1 = (const float*)d_in[4];
  const float* b1 = (const float*)d_in[5];
  const float* W2 = (const float*)d_in[6];
  const float* b2 = (const float*)d_in[7];
  float* out = (float*)d_out;
  char* ws = (char*)d_ws;

  // workspace layout (bytes), ~90.4 MB total
  unsigned short* hb = (unsigned short*)(ws + 0);         // 8,000,000 (h bf16)
  unsigned short* zB0 = (unsigned short*)(ws + 8000000);  // 8,000,000
  unsigned short* zB1 = (unsigned short*)(ws + 16000000); // 8,000,000
  unsigned short* Wt = (unsigned short*)(ws + 24000000);  // 262,144
  unsigned short* h1 = (unsigned short*)(ws + 24400000);  // 51,200,000
  int* counts = (int*)(ws + 75600000);                    // 400,000
  int* cursor = (int*)(ws + 76000000);                    // 400,000
  int* srs = (int*)(ws + 76400000);                       // 400,004 (+pad)
  int* bsum = (int*)(ws + 76800064);                      // 2,048
  int* binoff = (int*)(ws + 76802112);                    // 256
  int* perm = (int*)(ws + 76802624);                      // 400,000
  int* spos = (int*)(ws + 77202624);                      // 400,000
  int2* csr_pair = (int2*)(ws + 77602624);                // 12,800,000

  // zero counts + cursor (adjacent), and binoff
  zero_kernel<<<(2 * NN + 255) / 256, 256, 0, stream>>>(counts, 2 * NN);
  zero_kernel<<<1, 256, 0, stream>>>(binoff, 64);

  // MLP
  wt_kernel<<<(NFEATD * NHIDD) / 256, 256, 0, stream>>>(W1, Wt);
  gemm1_mfma_kernel<<<dim3(2, (NN + 127) / 128), 256, 0, stream>>>(x, Wt, b1, h1);
  gemm2_kernel<<<(NN + 63) / 64, 256, 0, stream>>>(h1, W2, b2, hb);

  // CSR build in degree-sorted row space
  count_kernel<<<(NE + 255) / 256, 256, 0, stream>>>(edst, counts);
  hist_kernel<<<(NN + 255) / 256, 256, 0, stream>>>(counts, binoff);
  binscan_kernel<<<1, 64, 0, stream>>>(binoff);
  scatter_rows_kernel<<<(NN + 255) / 256, 256, 0, stream>>>(counts, binoff, perm, spos);
  scan_blocks_kernel<<<NB, 256, 0, stream>>>(counts, perm, srs, bsum);
  scan_sums_kernel<<<1, 512, 0, stream>>>(bsum);
  add_off_kernel<<<NB, 256, 0, stream>>>(srs, bsum);
  scatter_kernel<<<(NE + 255) / 256, 256, 0, stream>>>(esrc, edst, eval, srs, spos,
                                                       cursor, csr_pair);

  // propagation: hb -> zB0 -> zB1 -> ... (10 hops, ends in zB1)
  const unsigned short* zin = hb;
  unsigned short* zout = zB0;
  for (int i = 0; i < KHOP; ++i) {
    prop_kernel<<<(NN * 5 + 255) / 256, 256, 0, stream>>>(srs, perm, csr_pair,
                                                          zin, hb, zout);
    if (i == 0) {
      zin = zB0;
      zout = zB1;
    } else {
      unsigned short* t = (unsigned short*)zin;
      zin = zout;
      zout = t;
    }
  }

  // log_softmax from bf16 z (hop 10 output = zB1) -> fp32 out
  lsm_kernel<<<(NN + 255) / 256, 256, 0, stream>>>(zB1, out);
}

// Round 5
// 1036.783 us; speedup vs baseline: 1.3986x; 1.3986x over previous
//
#include <hip/hip_runtime.h>
#include <hip/hip_bf16.h>
#include <math.h>

#define NN     100000
#define NFEATD 512
#define NHIDD  256
#define NCLS   40
#define NE     1600000
#define KHOP   10

typedef __attribute__((ext_vector_type(8))) short short8;
typedef __attribute__((ext_vector_type(4))) float floatx4;

// ---------- helpers ----------
static __device__ __forceinline__ float bf2f(unsigned int u) {
  unsigned int x = u << 16;
  float f;
  __builtin_memcpy(&f, &x, 4);
  return f;
}
static __device__ __forceinline__ unsigned short f2bf(float f) {
  unsigned int x;
  __builtin_memcpy(&x, &f, 4);
  x = (x + 0x7fffu + ((x >> 16) & 1u)) >> 16;
  return (unsigned short)x;
}
// 4 uints (8 packed bf16) -> 8 floats
static __device__ __forceinline__ void bf8_to_f(const uint4 u, float* f) {
  unsigned int a0 = u.x, a1 = u.y, a2 = u.z, a3 = u.w;
  unsigned int t;
  t = a0 << 16;          __builtin_memcpy(&f[0], &t, 4);
  t = a0 & 0xffff0000u;  __builtin_memcpy(&f[1], &t, 4);
  t = a1 << 16;          __builtin_memcpy(&f[2], &t, 4);
  t = a1 & 0xffff0000u;  __builtin_memcpy(&f[3], &t, 4);
  t = a2 << 16;          __builtin_memcpy(&f[4], &t, 4);
  t = a2 & 0xffff0000u;  __builtin_memcpy(&f[5], &t, 4);
  t = a3 << 16;          __builtin_memcpy(&f[6], &t, 4);
  t = a3 & 0xffff0000u;  __builtin_memcpy(&f[7], &t, 4);
}

// ---------- W1 [512][256] fp32 -> Wt [256][512] bf16 ----------
__global__ __launch_bounds__(256) void wt_kernel(const float* __restrict__ W1,
                                                 unsigned short* __restrict__ Wt) {
  int i = blockIdx.x * 256 + threadIdx.x;  // over 512*256
  int k = i >> 8;
  int n = i & 255;
  Wt[n * 512 + k] = f2bf(W1[i]);
}

// ---------- GEMM1 (MFMA, software-pipelined): h1 = relu(x @ W1 + b1) ----------
__global__ __launch_bounds__(256) void gemm1_mfma_kernel(
    const float* __restrict__ x, const unsigned short* __restrict__ Wt,
    const float* __restrict__ b1, unsigned short* __restrict__ h1) {
  __shared__ unsigned short As[128 * 40];  // row stride 40 shorts (80B)
  __shared__ unsigned short Bs[128 * 40];
  const int tid = threadIdx.x;
  const int lane = tid & 63;
  const int wave = tid >> 6;
  const int wr = wave >> 1, wc = wave & 1;
  const int m = lane & 15, quad = lane >> 4;
  const int c0 = blockIdx.x * 128;  // col block (0 or 128)
  const int r0 = blockIdx.y * 128;  // row block

  const int arow = tid >> 3;   // 0..31 (+rep*32)
  const int akq = tid & 7;     // float4 index within row (k = akq*4)
  const int brow = tid >> 2;   // 0..63 (+rep*64)
  const int bkq = tid & 3;     // 16B chunk within row (k = bkq*8)

  floatx4 acc[4][4];
#pragma unroll
  for (int i = 0; i < 4; ++i)
#pragma unroll
    for (int j = 0; j < 4; ++j) acc[i][j] = (floatx4){0.f, 0.f, 0.f, 0.f};

  float4 aR[4];
  uint4 bR[2];
#pragma unroll
  for (int rep = 0; rep < 4; ++rep) {
    int grow = r0 + arow + rep * 32;
    aR[rep] = make_float4(0.f, 0.f, 0.f, 0.f);
    if (grow < NN) aR[rep] = *(const float4*)(x + grow * NFEATD + akq * 4);
  }
#pragma unroll
  for (int rep = 0; rep < 2; ++rep)
    bR[rep] = *(const uint4*)(Wt + (c0 + brow + rep * 64) * NFEATD + bkq * 8);

  for (int kt = 0; kt < NFEATD; kt += 32) {
#pragma unroll
    for (int rep = 0; rep < 4; ++rep) {
      ushort4 o;
      o.x = f2bf(aR[rep].x);
      o.y = f2bf(aR[rep].y);
      o.z = f2bf(aR[rep].z);
      o.w = f2bf(aR[rep].w);
      *(ushort4*)&As[(arow + rep * 32) * 40 + akq * 4] = o;
    }
#pragma unroll
    for (int rep = 0; rep < 2; ++rep)
      *(uint4*)&Bs[(brow + rep * 64) * 40 + bkq * 8] = bR[rep];
    __syncthreads();

    int ktn = kt + 32;
    if (ktn < NFEATD) {
#pragma unroll
      for (int rep = 0; rep < 4; ++rep) {
        int grow = r0 + arow + rep * 32;
        float4 v = make_float4(0.f, 0.f, 0.f, 0.f);
        if (grow < NN) v = *(const float4*)(x + grow * NFEATD + ktn + akq * 4);
        aR[rep] = v;
      }
#pragma unroll
      for (int rep = 0; rep < 2; ++rep)
        bR[rep] = *(const uint4*)(Wt + (c0 + brow + rep * 64) * NFEATD + ktn + bkq * 8);
    }

    short8 af[4], bfr[4];
#pragma unroll
    for (int i = 0; i < 4; ++i)
      af[i] = *(const short8*)&As[(wr * 64 + i * 16 + m) * 40 + quad * 8];
#pragma unroll
    for (int j = 0; j < 4; ++j)
      bfr[j] = *(const short8*)&Bs[(wc * 64 + j * 16 + m) * 40 + quad * 8];
#pragma unroll
    for (int i = 0; i < 4; ++i)
#pragma unroll
      for (int j = 0; j < 4; ++j)
        acc[i][j] = __builtin_amdgcn_mfma_f32_16x16x32_bf16(af[i], bfr[j], acc[i][j], 0, 0, 0);
    __syncthreads();
  }

  float bias[4];
#pragma unroll
  for (int j = 0; j < 4; ++j) bias[j] = b1[c0 + wc * 64 + j * 16 + m];
#pragma unroll
  for (int i = 0; i < 4; ++i) {
#pragma unroll
    for (int r = 0; r < 4; ++r) {
      int row = r0 + wr * 64 + i * 16 + quad * 4 + r;
      if (row < NN) {
#pragma unroll
        for (int j = 0; j < 4; ++j) {
          float v = acc[i][j][r] + bias[j];
          h1[row * NHIDD + c0 + wc * 64 + j * 16 + m] = f2bf(fmaxf(v, 0.f));
        }
      }
    }
  }
}

// ---------- GEMM2: hb(bf16) = h1(bf16) @ W2 + b2 ----------
__global__ __launch_bounds__(256) void gemm2_kernel(
    const unsigned short* __restrict__ h1, const float* __restrict__ W2,
    const float* __restrict__ b2, unsigned short* __restrict__ hb) {
  __shared__ float w2s[NHIDD * NCLS];  // 40 KB
  __shared__ float b2s[NCLS];
  __shared__ unsigned short h1s[64 * 264];  // padded stride
  const int tid = threadIdx.x;
  const int r0 = blockIdx.x * 64;
  for (int i = tid; i < NHIDD * NCLS; i += 256) w2s[i] = W2[i];
  if (tid < NCLS) b2s[tid] = b2[tid];
#pragma unroll
  for (int q = 0; q < 8; ++q) {
    int l = tid + q * 256;
    int lr = l >> 5;
    int lc = (l & 31) << 3;
    int row = r0 + lr;
    uint4 v = make_uint4(0, 0, 0, 0);
    if (row < NN) v = *(const uint4*)(h1 + row * NHIDD + lc);
    *(uint4*)&h1s[lr * 264 + lc] = v;
  }
  __syncthreads();
  const int lr = tid >> 2;
  const int cq = (tid & 3) * 10;
  float acc[10];
#pragma unroll
  for (int j = 0; j < 10; ++j) acc[j] = 0.f;
#pragma unroll 4
  for (int k = 0; k < NHIDD; k += 2) {
    unsigned int hp = *(const unsigned int*)&h1s[lr * 264 + k];
    float a0 = bf2f(hp & 0xffffu);
    float a1 = bf2f(hp >> 16);
    const float* w0 = &w2s[k * NCLS + cq];
    const float* w1 = &w2s[(k + 1) * NCLS + cq];
#pragma unroll
    for (int j = 0; j < 10; ++j)
      acc[j] = fmaf(a1, w1[j], fmaf(a0, w0[j], acc[j]));
  }
  int row = r0 + lr;
  if (row < NN) {
#pragma unroll
    for (int jj = 0; jj < 5; ++jj) {
      unsigned int u = (unsigned int)f2bf(acc[2 * jj] + b2s[cq + 2 * jj]) |
                       ((unsigned int)f2bf(acc[2 * jj + 1] + b2s[cq + 2 * jj + 1]) << 16);
      *(unsigned int*)&hb[row * NCLS + cq + 2 * jj] = u;
    }
  }
}

// ---------- CSR build (degree-sorted row order, block-aggregated sort) ----------
__global__ __launch_bounds__(256) void zero_kernel(int* __restrict__ p, int n) {
  int i = blockIdx.x * 256 + threadIdx.x;
  if (i < n) p[i] = 0;
}
__global__ __launch_bounds__(256) void count_kernel(const int* __restrict__ edst,
                                                    int* __restrict__ counts) {
  int e = blockIdx.x * 256 + threadIdx.x;
  if (e < NE) atomicAdd(&counts[edst[e]], 1);
}
// block-local LDS histogram, one global atomic per (block, bin)
__global__ __launch_bounds__(256) void hist_kernel(const int* __restrict__ counts,
                                                   int* __restrict__ binoff) {
  __shared__ int lhist[64];
  int tid = threadIdx.x;
  if (tid < 64) lhist[tid] = 0;
  __syncthreads();
  int r = blockIdx.x * 256 + tid;
  if (r < NN) {
    int d = counts[r];
    if (d > 63) d = 63;
    atomicAdd(&lhist[d], 1);
  }
  __syncthreads();
  if (tid < 64) {
    int c = lhist[tid];
    if (c) atomicAdd(&binoff[tid], c);
  }
}
__global__ __launch_bounds__(64) void binscan_kernel(int* __restrict__ binoff) {
  __shared__ int s[64];
  int t = threadIdx.x;
  s[t] = binoff[t];
  __syncthreads();
  if (t == 0) {
    int run = 0;
    for (int i = 0; i < 64; ++i) {
      int c = s[i];
      s[i] = run;
      run += c;
    }
  }
  __syncthreads();
  binoff[t] = s[t];
}
// local rank via LDS atomics; block reserves a bin range with ONE global atomic
__global__ __launch_bounds__(256) void scatter_rows_kernel(
    const int* __restrict__ counts, int* __restrict__ binoff,
    int* __restrict__ perm, int* __restrict__ spos) {
  __shared__ int lhist[64];
  __shared__ int lbase[64];
  int tid = threadIdx.x;
  if (tid < 64) lhist[tid] = 0;
  __syncthreads();
  int r = blockIdx.x * 256 + tid;
  int d = 0, lrank = 0;
  bool valid = (r < NN);
  if (valid) {
    d = counts[r];
    if (d > 63) d = 63;
    lrank = atomicAdd(&lhist[d], 1);
  }
  __syncthreads();
  if (tid < 64) {
    int c = lhist[tid];
    lbase[tid] = c ? atomicAdd(&binoff[tid], c) : 0;
  }
  __syncthreads();
  if (valid) {
    int pos = lbase[d] + lrank;
    perm[pos] = r;
    spos[r] = pos;
  }
}
__global__ __launch_bounds__(256) void scan_blocks_kernel(
    const int* __restrict__ counts, const int* __restrict__ perm,
    int* __restrict__ srs, int* __restrict__ bsum) {
  __shared__ int s[256];
  int gid = blockIdx.x * 256 + threadIdx.x;
  int v = (gid < NN) ? counts[perm[gid]] : 0;
  s[threadIdx.x] = v;
  __syncthreads();
  for (int off = 1; off < 256; off <<= 1) {
    int t = (threadIdx.x >= off) ? s[threadIdx.x - off] : 0;
    __syncthreads();
    s[threadIdx.x] += t;
    __syncthreads();
  }
  if (gid < NN) srs[gid + 1] = s[threadIdx.x];
  if (threadIdx.x == 255) bsum[blockIdx.x] = s[255];
}
#define NB 391
__global__ __launch_bounds__(512) void scan_sums_kernel(int* __restrict__ bsum) {
  __shared__ int s[512];
  int tid = threadIdx.x;
  int v = (tid < NB) ? bsum[tid] : 0;
  s[tid] = v;
  __syncthreads();
  for (int off = 1; off < 512; off <<= 1) {
    int t = (tid >= off) ? s[tid - off] : 0;
    __syncthreads();
    s[tid] += t;
    __syncthreads();
  }
  if (tid < NB) bsum[tid] = (tid == 0) ? 0 : s[tid - 1];  // exclusive
}
__global__ __launch_bounds__(256) void add_off_kernel(int* __restrict__ srs,
                                                      const int* __restrict__ bsum) {
  int gid = blockIdx.x * 256 + threadIdx.x;
  if (gid < NN) srs[gid + 1] += bsum[blockIdx.x];
  if (gid == 0) srs[0] = 0;
}
__global__ __launch_bounds__(256) void scatter_kernel(
    const int* __restrict__ esrc, const int* __restrict__ edst,
    const float* __restrict__ eval, const int* __restrict__ srs,
    const int* __restrict__ spos, int* __restrict__ cursor,
    int2* __restrict__ csr_pair) {
  int e = blockIdx.x * 256 + threadIdx.x;
  if (e < NE) {
    int p = spos[edst[e]];
    int idx = srs[p] + atomicAdd(&cursor[p], 1);
    csr_pair[idx] = make_int2(esrc[e], __float_as_int(eval[e]));
  }
}

// ---------- propagation: zo[r] = 0.9 * (A z)[r] + 0.1 * h[r], bf16 ----------
__global__ __launch_bounds__(256) void prop_kernel(
    const int* __restrict__ srs, const int* __restrict__ perm,
    const int2* __restrict__ csr_pair, const unsigned short* __restrict__ zi,
    const unsigned short* __restrict__ hb, unsigned short* __restrict__ zo) {
  int t = blockIdx.x * 256 + threadIdx.x;
  if (t >= NN * 5) return;
  unsigned int p = (unsigned int)t / 5u;
  int cg8 = (t - (int)p * 5) * 8;  // col offset in bf16 elems
  int e0 = srs[p], e1 = srs[p + 1];
  int r = perm[p];
  float acc[8];
#pragma unroll
  for (int j = 0; j < 8; ++j) acc[j] = 0.f;

  int e = e0;
  for (; e + 8 <= e1; e += 8) {
    int2 pr[8];
#pragma unroll
    for (int q = 0; q < 8; ++q) pr[q] = csr_pair[e + q];
    uint4 g[8];
#pragma unroll
    for (int q = 0; q < 8; ++q)
      g[q] = *(const uint4*)(zi + pr[q].x * NCLS + cg8);
#pragma unroll
    for (int q = 0; q < 8; ++q) {
      float zf[8];
      bf8_to_f(g[q], zf);
      float v = __int_as_float(pr[q].y);
#pragma unroll
      for (int j = 0; j < 8; ++j) acc[j] = fmaf(v, zf[j], acc[j]);
    }
  }
  for (; e < e1; ++e) {
    int2 pr = csr_pair[e];
    uint4 g = *(const uint4*)(zi + pr.x * NCLS + cg8);
    float zf[8];
    bf8_to_f(g, zf);
    float v = __int_as_float(pr.y);
#pragma unroll
    for (int j = 0; j < 8; ++j) acc[j] = fmaf(v, zf[j], acc[j]);
  }

  uint4 hu = *(const uint4*)(hb + r * NCLS + cg8);
  float hf[8];
  bf8_to_f(hu, hf);
  uint4 o;
  unsigned int w[4];
#pragma unroll
  for (int i = 0; i < 4; ++i) {
    unsigned int lo = f2bf(0.9f * acc[2 * i] + 0.1f * hf[2 * i]);
    unsigned int hi = f2bf(0.9f * acc[2 * i + 1] + 0.1f * hf[2 * i + 1]);
    w[i] = lo | (hi << 16);
  }
  o.x = w[0];
  o.y = w[1];
  o.z = w[2];
  o.w = w[3];
  *(uint4*)(zo + r * NCLS + cg8) = o;
}

// ---------- log_softmax: bf16 z -> fp32 out ----------
__global__ __launch_bounds__(256) void lsm_kernel(const unsigned short* __restrict__ zf,
                                                  float* __restrict__ out) {
  int r = blockIdx.x * 256 + threadIdx.x;
  if (r >= NN) return;
  float v[NCLS];
#pragma unroll
  for (int q = 0; q < 5; ++q) {
    uint4 u = *(const uint4*)(zf + r * NCLS + q * 8);
    bf8_to_f(u, v + q * 8);
  }
  float m = v[0];
#pragma unroll
  for (int i = 1; i < NCLS; ++i) m = fmaxf(m, v[i]);
  float ssum = 0.f;
#pragma unroll
  for (int i = 0; i < NCLS; ++i) ssum += expf(v[i] - m);
  float lse = m + logf(ssum);
#pragma unroll
  for (int q = 0; q < 10; ++q) {
    float4 o;
    o.x = v[q * 4 + 0] - lse;
    o.y = v[q * 4 + 1] - lse;
    o.z = v[q * 4 + 2] - lse;
    o.w = v[q * 4 + 3] - lse;
    *(float4*)(out + r * NCLS + q * 4) = o;
  }
}

extern "C" void kernel_launch(void* const* d_in, const int* in_sizes, int n_in,
                              void* d_out, int out_size, void* d_ws, size_t ws_size,
                              hipStream_t stream) {
  const float* x = (const float*)d_in[0];
  const int* esrc = (const int*)d_in[1];
  const int* edst = (const int*)d_in[2];
  const float* eval = (const float*)d_in[3];
  const float* W1 = (const float*)d_in[4];
  const float* b1 = (const float*)d_in[5];
  const float* W2 = (const float*)d_in[6];
  const float* b2 = (const float*)d_in[7];
  float* out = (float*)d_out;
  char* ws = (char*)d_ws;

  // workspace layout (bytes), ~90.4 MB total
  unsigned short* hb = (unsigned short*)(ws + 0);         // 8,000,000 (h bf16)
  unsigned short* zB0 = (unsigned short*)(ws + 8000000);  // 8,000,000
  unsigned short* zB1 = (unsigned short*)(ws + 16000000); // 8,000,000
  unsigned short* Wt = (unsigned short*)(ws + 24000000);  // 262,144
  unsigned short* h1 = (unsigned short*)(ws + 24400000);  // 51,200,000
  int* counts = (int*)(ws + 75600000);                    // 400,000
  int* cursor = (int*)(ws + 76000000);                    // 400,000
  int* srs = (int*)(ws + 76400000);                       // 400,004 (+pad)
  int* bsum = (int*)(ws + 76800064);                      // 2,048
  int* binoff = (int*)(ws + 76802112);                    // 256
  int* perm = (int*)(ws + 76802624);                      // 400,000
  int* spos = (int*)(ws + 77202624);                      // 400,000
  int2* csr_pair = (int2*)(ws + 77602624);                // 12,800,000

  // zero counts + cursor (adjacent), and binoff
  zero_kernel<<<(2 * NN + 255) / 256, 256, 0, stream>>>(counts, 2 * NN);
  zero_kernel<<<1, 256, 0, stream>>>(binoff, 64);

  // MLP
  wt_kernel<<<(NFEATD * NHIDD) / 256, 256, 0, stream>>>(W1, Wt);
  gemm1_mfma_kernel<<<dim3(2, (NN + 127) / 128), 256, 0, stream>>>(x, Wt, b1, h1);
  gemm2_kernel<<<(NN + 63) / 64, 256, 0, stream>>>(h1, W2, b2, hb);

  // CSR build in degree-sorted row space
  count_kernel<<<(NE + 255) / 256, 256, 0, stream>>>(edst, counts);
  hist_kernel<<<(NN + 255) / 256, 256, 0, stream>>>(counts, binoff);
  binscan_kernel<<<1, 64, 0, stream>>>(binoff);
  scatter_rows_kernel<<<(NN + 255) / 256, 256, 0, stream>>>(counts, binoff, perm, spos);
  scan_blocks_kernel<<<NB, 256, 0, stream>>>(counts, perm, srs, bsum);
  scan_sums_kernel<<<1, 512, 0, stream>>>(bsum);
  add_off_kernel<<<NB, 256, 0, stream>>>(srs, bsum);
  scatter_kernel<<<(NE + 255) / 256, 256, 0, stream>>>(esrc, edst, eval, srs, spos,
                                                       cursor, csr_pair);

  // propagation: hb -> zB0 -> zB1 -> ... (10 hops, ends in zB1)
  const unsigned short* zin = hb;
  unsigned short* zout = zB0;
  for (int i = 0; i < KHOP; ++i) {
    prop_kernel<<<(NN * 5 + 255) / 256, 256, 0, stream>>>(srs, perm, csr_pair,
                                                          zin, hb, zout);
    if (i == 0) {
      zin = zB0;
      zout = zB1;
    } else {
      unsigned short* t = (unsigned short*)zin;
      zin = zout;
      zout = t;
    }
  }

  // log_softmax from bf16 z (hop 10 output = zB1) -> fp32 out
  lsm_kernel<<<(NN + 255) / 256, 256, 0, stream>>>(zB1, out);
}